// Round 1
// baseline (2777.488 us; speedup 1.0000x reference)
//
#include <hip/hip_runtime.h>
#include <hip/hip_bf16.h>
#include <cstdint>

// MCRNNVAE eval forward, algebraically collapsed:
//   h_{t+1} = tanh(x_t@R_c + r0_c + h_t@Q_c)
//   mu_t    = x_t@N_c + h_t@M2_c + n0_c
// R,Q,N,M2,r0,n0 precomputed from the raw weights (exact linear algebra).

__device__ __forceinline__ float bf2f(unsigned short u){
  union { unsigned int i; float f; } v; v.i = ((unsigned int)u) << 16; return v.f;
}
__device__ __forceinline__ unsigned short f2bf(float f){
  union { float f; unsigned int i; } v; v.f = f;
  unsigned int r = v.i + 0x7fffu + ((v.i >> 16) & 1u);
  return (unsigned short)(r >> 16);
}

__device__ __forceinline__ float dotSB(const float* __restrict__ a,
                                       const float* __restrict__ b, int K, int ldb){
  float s = 0.f;
  #pragma unroll 4
  for (int k = 0; k < K; ++k) s = fmaf(a[k], b[(size_t)k * ldb], s);
  return s;
}

// ---- precompute stage 1: T1 = We1@Wqm, T2 = We2@Wqm, c0a = be@Wqm + bqm
__global__ void pre1(const float* __restrict__ encW, const float* __restrict__ encb,
                     const float* __restrict__ Wqm, const float* __restrict__ bqm,
                     float* __restrict__ T1, float* __restrict__ T2, float* __restrict__ c0a){
  int i = blockIdx.x * 256 + threadIdx.x;
  if (i < 24576){                       // T1[c][rr][l], 3*128*64
    int c = i >> 13, rr = (i >> 6) & 127, l = i & 63;
    T1[i] = dotSB(encW + ((size_t)c*384 + rr)*128, Wqm + (size_t)c*8192 + l, 128, 64);
  } else if (i < 73728){                // T2[c][rr][l], 3*256*64
    int j = i - 24576; int c = j >> 14, rr = (j >> 6) & 255, l = j & 63;
    T2[j] = dotSB(encW + ((size_t)c*384 + 128 + rr)*128, Wqm + (size_t)c*8192 + l, 128, 64);
  } else if (i < 73920){                // c0a[c][l], 3*64
    int j = i - 73728; int c = j >> 6, l = j & 63;
    c0a[j] = dotSB(encb + c*128, Wqm + (size_t)c*8192 + l, 128, 64) + bqm[j];
  }
}

// ---- stage 2: A = T1@Wz, Bm = T2@Wz, c0 = c0a@Wz + bz
__global__ void pre2(const float* __restrict__ T1, const float* __restrict__ T2,
                     const float* __restrict__ c0a, const float* __restrict__ Wz,
                     const float* __restrict__ bz,
                     float* __restrict__ A, float* __restrict__ Bm, float* __restrict__ c0){
  int i = blockIdx.x * 256 + threadIdx.x;
  if (i < 49152){                       // A[c][rr][n], 3*128*128
    int c = i >> 14, rr = (i >> 7) & 127, n = i & 127;
    A[i] = dotSB(T1 + ((size_t)c*128 + rr)*64, Wz + n, 64, 128);
  } else if (i < 147456){               // Bm[c][rr][n], 3*256*128
    int j = i - 49152; int c = j >> 15, rr = (j >> 7) & 255, n = j & 127;
    Bm[j] = dotSB(T2 + ((size_t)c*256 + rr)*64, Wz + n, 64, 128);
  } else if (i < 147840){               // c0[c][n], 3*128
    int j = i - 147456; int c = j >> 7, n = j & 127;
    c0[j] = dotSB(c0a + c*64, Wz + n, 64, 128) + bz[n];
  }
}

// ---- stage 3: P = Wi1 + A@Wi2; Q = Whh + Bm@Wi2; r = c0@Wi2 + bih + bhh;
//               D1 = A@Wd1; E1 = Wd2 + Bm@Wd1; m0a = c0@Wd1 + bd
__global__ void pre3(const float* __restrict__ A, const float* __restrict__ Bm,
                     const float* __restrict__ c0, const float* __restrict__ Wih,
                     const float* __restrict__ Whh, const float* __restrict__ bih,
                     const float* __restrict__ bhh, const float* __restrict__ decW,
                     const float* __restrict__ decb,
                     float* __restrict__ P, float* __restrict__ Q, float* __restrict__ r,
                     float* __restrict__ D1, float* __restrict__ E1, float* __restrict__ m0a){
  int i = blockIdx.x * 256 + threadIdx.x;
  const float* Wi2 = Wih + 128*256;
  if (i < 98304){                       // P[c][rr][n], 3*128*256
    int c = i >> 15, rr = (i >> 8) & 127, n = i & 255;
    P[i] = Wih[rr*256 + n] + dotSB(A + ((size_t)c*128 + rr)*128, Wi2 + n, 128, 256);
  } else if (i < 294912){               // Q[c][rr][n], 3*256*256
    int j = i - 98304; int c = j >> 16, rr = (j >> 8) & 255, n = j & 255;
    Q[j] = Whh[rr*256 + n] + dotSB(Bm + ((size_t)c*256 + rr)*128, Wi2 + n, 128, 256);
  } else if (i < 295680){               // r[c][n], 3*256
    int j = i - 294912; int c = j >> 8, n = j & 255;
    r[j] = dotSB(c0 + c*128, Wi2 + n, 128, 256) + bih[n] + bhh[n];
  } else if (i < 344832){               // D1[c][rr][n], 3*128*128
    int j = i - 295680; int c = j >> 14, rr = (j >> 7) & 127, n = j & 127;
    D1[j] = dotSB(A + ((size_t)c*128 + rr)*128, decW + (size_t)c*49152 + n, 128, 128);
  } else if (i < 443136){               // E1[c][rr][n], 3*256*128
    int j = i - 344832; int c = j >> 15, rr = (j >> 7) & 255, n = j & 127;
    E1[j] = decW[(size_t)c*49152 + (size_t)(128 + rr)*128 + n]
          + dotSB(Bm + ((size_t)c*256 + rr)*128, decW + (size_t)c*49152 + n, 128, 128);
  } else if (i < 443520){               // m0a[c][n], 3*128
    int j = i - 443136; int c = j >> 7, n = j & 127;
    m0a[j] = dotSB(c0 + c*128, decW + (size_t)c*49152 + n, 128, 128) + decb[j];
  }
}

// ---- stage 4: R = Wx@P; r0 = bx@P + r; M1 = D1@Wpm; M2 = E1@Wpm; m0 = m0a@Wpm + bpm
__global__ void pre4(const float* __restrict__ Wx, const float* __restrict__ bx,
                     const float* __restrict__ P, const float* __restrict__ r,
                     const float* __restrict__ D1, const float* __restrict__ E1,
                     const float* __restrict__ m0a, const float* __restrict__ Wpm,
                     const float* __restrict__ bpm,
                     float* __restrict__ R, float* __restrict__ r0,
                     float* __restrict__ M1, float* __restrict__ M2, float* __restrict__ m0){
  int i = blockIdx.x * 256 + threadIdx.x;
  if (i < 98304){                       // R[c][rr][n], 3*128*256
    int c = i >> 15, rr = (i >> 8) & 127, n = i & 255;
    R[i] = dotSB(Wx + ((size_t)c*128 + rr)*128, P + (size_t)c*32768 + n, 128, 256);
  } else if (i < 99072){                // r0[c][n], 3*256
    int j = i - 98304; int c = j >> 8, n = j & 255;
    r0[j] = dotSB(bx + c*128, P + (size_t)c*32768 + n, 128, 256) + r[j];
  } else if (i < 148224){               // M1[c][rr][n], 3*128*128
    int j = i - 99072; int c = j >> 14, rr = (j >> 7) & 127, n = j & 127;
    M1[j] = dotSB(D1 + ((size_t)c*128 + rr)*128, Wpm + (size_t)c*16384 + n, 128, 128);
  } else if (i < 246528){               // M2[c][rr][n], 3*256*128
    int j = i - 148224; int c = j >> 15, rr = (j >> 7) & 255, n = j & 127;
    M2[j] = dotSB(E1 + ((size_t)c*256 + rr)*128, Wpm + (size_t)c*16384 + n, 128, 128);
  } else if (i < 246912){               // m0[c][n], 3*128
    int j = i - 246528; int c = j >> 7, n = j & 127;
    m0[j] = dotSB(m0a + c*128, Wpm + (size_t)c*16384 + n, 128, 128) + bpm[j];
  }
}

// ---- stage 5: Nn = Wx@M1; n0 = bx@M1 + m0
__global__ void pre5(const float* __restrict__ Wx, const float* __restrict__ bx,
                     const float* __restrict__ M1, const float* __restrict__ m0,
                     float* __restrict__ Nn, float* __restrict__ n0){
  int i = blockIdx.x * 256 + threadIdx.x;
  if (i < 49152){                       // Nn[c][rr][n], 3*128*128
    int c = i >> 14, rr = (i >> 7) & 127, n = i & 127;
    Nn[i] = dotSB(Wx + ((size_t)c*128 + rr)*128, M1 + (size_t)c*16384 + n, 128, 128);
  } else if (i < 49536){                // n0[c][n], 3*128
    int j = i - 49152; int c = j >> 7, n = j & 127;
    n0[j] = dotSB(bx + c*128, M1 + (size_t)c*16384 + n, 128, 128) + m0[j];
  }
}

// ---- U[c,t,b,:] = x_row@R_c + r0_c, stored bf16. 32 rows/block, col = tid.
__global__ void kernU(const float* __restrict__ x, const float* __restrict__ R,
                      const float* __restrict__ r0, unsigned short* __restrict__ U){
  const int m0 = blockIdx.x * 32;              // 51200/32=1600: no channel straddle
  const int col = threadIdx.x;                 // 0..255
  const int c = m0 / 51200;
  const float* __restrict__ Rc = R + (size_t)c * 32768;
  const float* __restrict__ xb = x + (size_t)m0 * 128;
  float acc[32];
  const float rz = r0[c*256 + col];
  #pragma unroll
  for (int rr = 0; rr < 32; ++rr) acc[rr] = rz;
  for (int k = 0; k < 128; k += 4){
    float rk0 = Rc[(k+0)*256 + col];
    float rk1 = Rc[(k+1)*256 + col];
    float rk2 = Rc[(k+2)*256 + col];
    float rk3 = Rc[(k+3)*256 + col];
    #pragma unroll
    for (int rr = 0; rr < 32; ++rr){
      const float* xr = xb + rr*128 + k;       // wave-uniform -> scalar loads
      acc[rr] = fmaf(xr[0], rk0, acc[rr]);
      acc[rr] = fmaf(xr[1], rk1, acc[rr]);
      acc[rr] = fmaf(xr[2], rk2, acc[rr]);
      acc[rr] = fmaf(xr[3], rk3, acc[rr]);
    }
  }
  unsigned short* Ub = U + (size_t)m0 * 256 + col;
  #pragma unroll
  for (int rr = 0; rr < 32; ++rr) Ub[(size_t)rr * 256] = f2bf(acc[rr]);
}

// ---- recurrence: h_{t+1} = tanh(U_t + h_t@Q_c); stores h_t (pre-update) to Hs (bf16).
// grid 3*64 blocks, 512 threads = 8 waves, wave w owns batch row b0+w; lane owns 4 cols.
__global__ void kernB(const unsigned short* __restrict__ U, const float* __restrict__ Q,
                      const float* __restrict__ h0, unsigned short* __restrict__ Hs){
  __shared__ float hs[8][256];
  const int c    = blockIdx.x >> 6;
  const int b0   = (blockIdx.x & 63) << 3;
  const int w    = threadIdx.x >> 6;
  const int lane = threadIdx.x & 63;
  const int col  = lane << 2;
  const float* __restrict__ Qc = Q + (size_t)c * 65536;
  const int b = b0 + w;
  float hr0, hr1, hr2, hr3;
  {
    const float4 hv = *(const float4*)(h0 + ((size_t)c*512 + b)*256 + col);
    hr0 = hv.x; hr1 = hv.y; hr2 = hv.z; hr3 = hv.w;
    *(float4*)&hs[w][col] = hv;
  }
  __syncthreads();
  for (int t = 0; t < 100; ++t){
    const size_t rowoff = ((size_t)(c*100 + t)*512 + b)*256 + col;
    ushort4 pk; pk.x = f2bf(hr0); pk.y = f2bf(hr1); pk.z = f2bf(hr2); pk.w = f2bf(hr3);
    *(ushort4*)(Hs + rowoff) = pk;             // h_t (pre-update) -> mus use this
    ushort4 uv = *(const ushort4*)(U + rowoff);
    float a0 = bf2f(uv.x), a1 = bf2f(uv.y), a2 = bf2f(uv.z), a3 = bf2f(uv.w);
    #pragma unroll 4
    for (int k = 0; k < 256; k += 4){
      const float4 hv = *(const float4*)&hs[w][k];            // broadcast read
      const float4 q0 = *(const float4*)(Qc + (size_t)(k+0)*256 + col);
      const float4 q1 = *(const float4*)(Qc + (size_t)(k+1)*256 + col);
      const float4 q2 = *(const float4*)(Qc + (size_t)(k+2)*256 + col);
      const float4 q3 = *(const float4*)(Qc + (size_t)(k+3)*256 + col);
      a0 = fmaf(hv.x,q0.x,a0); a1 = fmaf(hv.x,q0.y,a1); a2 = fmaf(hv.x,q0.z,a2); a3 = fmaf(hv.x,q0.w,a3);
      a0 = fmaf(hv.y,q1.x,a0); a1 = fmaf(hv.y,q1.y,a1); a2 = fmaf(hv.y,q1.z,a2); a3 = fmaf(hv.y,q1.w,a3);
      a0 = fmaf(hv.z,q2.x,a0); a1 = fmaf(hv.z,q2.y,a1); a2 = fmaf(hv.z,q2.z,a2); a3 = fmaf(hv.z,q2.w,a3);
      a0 = fmaf(hv.w,q3.x,a0); a1 = fmaf(hv.w,q3.y,a1); a2 = fmaf(hv.w,q3.z,a2); a3 = fmaf(hv.w,q3.w,a3);
    }
    hr0 = tanhf(a0); hr1 = tanhf(a1); hr2 = tanhf(a2); hr3 = tanhf(a3);
    __syncthreads();                           // all reads of h_t done
    *(float4*)&hs[w][col] = make_float4(hr0, hr1, hr2, hr3);
    __syncthreads();                           // h_{t+1} visible
  }
}

// ---- out[c,t,b,:] = x_row@Nn_c + Hs_row@M2_c + n0_c. 32 rows/block, 128 threads.
__global__ void kernC(const float* __restrict__ x, const unsigned short* __restrict__ Hs,
                      const float* __restrict__ Nn, const float* __restrict__ M2,
                      const float* __restrict__ n0, float* __restrict__ out){
  const int m0 = blockIdx.x * 32;
  const int col = threadIdx.x;                 // 0..127
  const int c = m0 / 51200;
  const float* __restrict__ Nc  = Nn + (size_t)c * 16384;
  const float* __restrict__ M2c = M2 + (size_t)c * 32768;
  const float* __restrict__ xb  = x + (size_t)m0 * 128;
  const uint32_t* __restrict__ Hb = (const uint32_t*)(Hs + (size_t)m0 * 256);
  float acc[32];
  const float nz = n0[c*128 + col];
  #pragma unroll
  for (int rr = 0; rr < 32; ++rr) acc[rr] = nz;
  for (int k = 0; k < 128; k += 2){
    float nk0 = Nc[(k+0)*128 + col];
    float nk1 = Nc[(k+1)*128 + col];
    #pragma unroll
    for (int rr = 0; rr < 32; ++rr){
      const float* xr = xb + rr*128 + k;
      acc[rr] = fmaf(xr[0], nk0, acc[rr]);
      acc[rr] = fmaf(xr[1], nk1, acc[rr]);
    }
  }
  for (int kp = 0; kp < 128; ++kp){
    float mk0 = M2c[(size_t)(2*kp+0)*128 + col];
    float mk1 = M2c[(size_t)(2*kp+1)*128 + col];
    #pragma unroll
    for (int rr = 0; rr < 32; ++rr){
      uint32_t v = Hb[rr*128 + kp];            // wave-uniform scalar load, 2 bf16
      union{uint32_t i; float f;} lo, hi;
      lo.i = v << 16; hi.i = v & 0xffff0000u;
      acc[rr] = fmaf(lo.f, mk0, acc[rr]);
      acc[rr] = fmaf(hi.f, mk1, acc[rr]);
    }
  }
  float* ob = out + (size_t)m0 * 128 + col;
  #pragma unroll
  for (int rr = 0; rr < 32; ++rr) ob[(size_t)rr * 128] = acc[rr];
}

extern "C" void kernel_launch(void* const* d_in, const int* in_sizes, int n_in,
                              void* d_out, int out_size, void* d_ws, size_t ws_size,
                              hipStream_t stream){
  const float* x    = (const float*)d_in[0];
  const float* Wx   = (const float*)d_in[1];
  const float* bx   = (const float*)d_in[2];
  const float* encW = (const float*)d_in[3];
  const float* encb = (const float*)d_in[4];
  const float* Wqm  = (const float*)d_in[5];
  const float* bqm  = (const float*)d_in[6];
  const float* Wz   = (const float*)d_in[7];
  const float* bz   = (const float*)d_in[8];
  const float* decW = (const float*)d_in[9];
  const float* decb = (const float*)d_in[10];
  const float* Wpm  = (const float*)d_in[11];
  const float* bpm  = (const float*)d_in[12];
  const float* Wih  = (const float*)d_in[13];
  const float* Whh  = (const float*)d_in[14];
  const float* bih  = (const float*)d_in[15];
  const float* bhh  = (const float*)d_in[16];
  const float* h0   = (const float*)d_in[17];

  float* ws = (float*)d_ws;
  size_t off = 0;
  auto alloc = [&](size_t n){ float* p = ws + off; off += n; return p; };
  float* T1  = alloc(24576);  float* T2  = alloc(49152);  float* c0a = alloc(192);
  float* A   = alloc(49152);  float* Bm  = alloc(98304);  float* c0  = alloc(384);
  float* P   = alloc(98304);  float* Q   = alloc(196608); float* r   = alloc(768);
  float* D1  = alloc(49152);  float* E1  = alloc(98304);  float* m0a = alloc(384);
  float* R   = alloc(98304);  float* r0  = alloc(768);
  float* M1  = alloc(49152);  float* M2  = alloc(98304);  float* m0  = alloc(384);
  float* Nn  = alloc(49152);  float* n0  = alloc(384);
  // U (bf16, 39.3M elems) lives in d_out's buffer (exactly 78.6MB); consumed by
  // kernB before kernC overwrites d_out with the final result.
  unsigned short* U  = (unsigned short*)d_out;
  unsigned short* Hs = (unsigned short*)(ws + off); off += 19660800;  // bf16 in float slots

  hipLaunchKernelGGL(pre1, dim3(289),  dim3(256), 0, stream, encW, encb, Wqm, bqm, T1, T2, c0a);
  hipLaunchKernelGGL(pre2, dim3(578),  dim3(256), 0, stream, T1, T2, c0a, Wz, bz, A, Bm, c0);
  hipLaunchKernelGGL(pre3, dim3(1733), dim3(256), 0, stream, A, Bm, c0, Wih, Whh, bih, bhh,
                     decW, decb, P, Q, r, D1, E1, m0a);
  hipLaunchKernelGGL(pre4, dim3(965),  dim3(256), 0, stream, Wx, bx, P, r, D1, E1, m0a,
                     Wpm, bpm, R, r0, M1, M2, m0);
  hipLaunchKernelGGL(pre5, dim3(194),  dim3(256), 0, stream, Wx, bx, M1, m0, Nn, n0);
  hipLaunchKernelGGL(kernU, dim3(4800), dim3(256), 0, stream, x, R, r0, U);
  hipLaunchKernelGGL(kernB, dim3(192),  dim3(512), 0, stream, U, Q, h0, Hs);
  hipLaunchKernelGGL(kernC, dim3(4800), dim3(128), 0, stream, x, Hs, Nn, M2, n0, (float*)d_out);
}

// Round 2
// 1365.770 us; speedup vs baseline: 2.0336x; 2.0336x over previous
//
#include <hip/hip_runtime.h>
#include <hip/hip_bf16.h>
#include <cstdint>

// MCRNNVAE eval forward, algebraically collapsed:
//   h_{t+1} = tanh(x_t@R_c + r0_c + h_t@Q_c)
//   mu_t    = x_t@N_c + h_t@M2_c + n0_c
// R,Q,N,M2,r0,n0 precomputed from the raw weights (exact linear algebra).
// Round 2: kernB rewritten with MFMA (Q register-resident bf16, h split hi+lo bf16).

typedef __attribute__((ext_vector_type(8))) short short8;
typedef __attribute__((ext_vector_type(4))) float float4v;

__device__ __forceinline__ float bf2f(unsigned short u){
  union { unsigned int i; float f; } v; v.i = ((unsigned int)u) << 16; return v.f;
}
__device__ __forceinline__ unsigned short f2bf(float f){
  union { float f; unsigned int i; } v; v.f = f;
  unsigned int r = v.i + 0x7fffu + ((v.i >> 16) & 1u);
  return (unsigned short)(r >> 16);
}
__device__ __forceinline__ float ftanh(float x){
  x = fminf(15.f, fmaxf(-15.f, x));
  float e = __expf(2.f * x);                      // v_exp_f32 path
  return (e - 1.f) * __builtin_amdgcn_rcpf(e + 1.f);
}

__device__ __forceinline__ float dotSB(const float* __restrict__ a,
                                       const float* __restrict__ b, int K, int ldb){
  float s = 0.f;
  #pragma unroll 4
  for (int k = 0; k < K; ++k) s = fmaf(a[k], b[(size_t)k * ldb], s);
  return s;
}

// ---- precompute stage 1: T1 = We1@Wqm, T2 = We2@Wqm, c0a = be@Wqm + bqm
__global__ void pre1(const float* __restrict__ encW, const float* __restrict__ encb,
                     const float* __restrict__ Wqm, const float* __restrict__ bqm,
                     float* __restrict__ T1, float* __restrict__ T2, float* __restrict__ c0a){
  int i = blockIdx.x * 256 + threadIdx.x;
  if (i < 24576){                       // T1[c][rr][l], 3*128*64
    int c = i >> 13, rr = (i >> 6) & 127, l = i & 63;
    T1[i] = dotSB(encW + ((size_t)c*384 + rr)*128, Wqm + (size_t)c*8192 + l, 128, 64);
  } else if (i < 73728){                // T2[c][rr][l], 3*256*64
    int j = i - 24576; int c = j >> 14, rr = (j >> 6) & 255, l = j & 63;
    T2[j] = dotSB(encW + ((size_t)c*384 + 128 + rr)*128, Wqm + (size_t)c*8192 + l, 128, 64);
  } else if (i < 73920){                // c0a[c][l], 3*64
    int j = i - 73728; int c = j >> 6, l = j & 63;
    c0a[j] = dotSB(encb + c*128, Wqm + (size_t)c*8192 + l, 128, 64) + bqm[j];
  }
}

// ---- stage 2: A = T1@Wz, Bm = T2@Wz, c0 = c0a@Wz + bz
__global__ void pre2(const float* __restrict__ T1, const float* __restrict__ T2,
                     const float* __restrict__ c0a, const float* __restrict__ Wz,
                     const float* __restrict__ bz,
                     float* __restrict__ A, float* __restrict__ Bm, float* __restrict__ c0){
  int i = blockIdx.x * 256 + threadIdx.x;
  if (i < 49152){                       // A[c][rr][n], 3*128*128
    int c = i >> 14, rr = (i >> 7) & 127, n = i & 127;
    A[i] = dotSB(T1 + ((size_t)c*128 + rr)*64, Wz + n, 64, 128);
  } else if (i < 147456){               // Bm[c][rr][n], 3*256*128
    int j = i - 49152; int c = j >> 15, rr = (j >> 7) & 255, n = j & 127;
    Bm[j] = dotSB(T2 + ((size_t)c*256 + rr)*64, Wz + n, 64, 128);
  } else if (i < 147840){               // c0[c][n], 3*128
    int j = i - 147456; int c = j >> 7, n = j & 127;
    c0[j] = dotSB(c0a + c*64, Wz + n, 64, 128) + bz[n];
  }
}

// ---- stage 3: P = Wi1 + A@Wi2; Q = Whh + Bm@Wi2; r = c0@Wi2 + bih + bhh;
//               D1 = A@Wd1; E1 = Wd2 + Bm@Wd1; m0a = c0@Wd1 + bd
__global__ void pre3(const float* __restrict__ A, const float* __restrict__ Bm,
                     const float* __restrict__ c0, const float* __restrict__ Wih,
                     const float* __restrict__ Whh, const float* __restrict__ bih,
                     const float* __restrict__ bhh, const float* __restrict__ decW,
                     const float* __restrict__ decb,
                     float* __restrict__ P, float* __restrict__ Q, float* __restrict__ r,
                     float* __restrict__ D1, float* __restrict__ E1, float* __restrict__ m0a){
  int i = blockIdx.x * 256 + threadIdx.x;
  const float* Wi2 = Wih + 128*256;
  if (i < 98304){                       // P[c][rr][n], 3*128*256
    int c = i >> 15, rr = (i >> 8) & 127, n = i & 255;
    P[i] = Wih[rr*256 + n] + dotSB(A + ((size_t)c*128 + rr)*128, Wi2 + n, 128, 256);
  } else if (i < 294912){               // Q[c][rr][n], 3*256*256
    int j = i - 98304; int c = j >> 16, rr = (j >> 8) & 255, n = j & 255;
    Q[j] = Whh[rr*256 + n] + dotSB(Bm + ((size_t)c*256 + rr)*128, Wi2 + n, 128, 256);
  } else if (i < 295680){               // r[c][n], 3*256
    int j = i - 294912; int c = j >> 8, n = j & 255;
    r[j] = dotSB(c0 + c*128, Wi2 + n, 128, 256) + bih[n] + bhh[n];
  } else if (i < 344832){               // D1[c][rr][n], 3*128*128
    int j = i - 295680; int c = j >> 14, rr = (j >> 7) & 127, n = j & 127;
    D1[j] = dotSB(A + ((size_t)c*128 + rr)*128, decW + (size_t)c*49152 + n, 128, 128);
  } else if (i < 443136){               // E1[c][rr][n], 3*256*128
    int j = i - 344832; int c = j >> 15, rr = (j >> 7) & 255, n = j & 127;
    E1[j] = decW[(size_t)c*49152 + (size_t)(128 + rr)*128 + n]
          + dotSB(Bm + ((size_t)c*256 + rr)*128, decW + (size_t)c*49152 + n, 128, 128);
  } else if (i < 443520){               // m0a[c][n], 3*128
    int j = i - 443136; int c = j >> 7, n = j & 127;
    m0a[j] = dotSB(c0 + c*128, decW + (size_t)c*49152 + n, 128, 128) + decb[j];
  }
}

// ---- stage 4: R = Wx@P; r0 = bx@P + r; M1 = D1@Wpm; M2 = E1@Wpm; m0 = m0a@Wpm + bpm
__global__ void pre4(const float* __restrict__ Wx, const float* __restrict__ bx,
                     const float* __restrict__ P, const float* __restrict__ r,
                     const float* __restrict__ D1, const float* __restrict__ E1,
                     const float* __restrict__ m0a, const float* __restrict__ Wpm,
                     const float* __restrict__ bpm,
                     float* __restrict__ R, float* __restrict__ r0,
                     float* __restrict__ M1, float* __restrict__ M2, float* __restrict__ m0){
  int i = blockIdx.x * 256 + threadIdx.x;
  if (i < 98304){                       // R[c][rr][n], 3*128*256
    int c = i >> 15, rr = (i >> 8) & 127, n = i & 255;
    R[i] = dotSB(Wx + ((size_t)c*128 + rr)*128, P + (size_t)c*32768 + n, 128, 256);
  } else if (i < 99072){                // r0[c][n], 3*256
    int j = i - 98304; int c = j >> 8, n = j & 255;
    r0[j] = dotSB(bx + c*128, P + (size_t)c*32768 + n, 128, 256) + r[j];
  } else if (i < 148224){               // M1[c][rr][n], 3*128*128
    int j = i - 99072; int c = j >> 14, rr = (j >> 7) & 127, n = j & 127;
    M1[j] = dotSB(D1 + ((size_t)c*128 + rr)*128, Wpm + (size_t)c*16384 + n, 128, 128);
  } else if (i < 246528){               // M2[c][rr][n], 3*256*128
    int j = i - 148224; int c = j >> 15, rr = (j >> 7) & 255, n = j & 127;
    M2[j] = dotSB(E1 + ((size_t)c*256 + rr)*128, Wpm + (size_t)c*16384 + n, 128, 128);
  } else if (i < 246912){               // m0[c][n], 3*128
    int j = i - 246528; int c = j >> 7, n = j & 127;
    m0[j] = dotSB(m0a + c*128, Wpm + (size_t)c*16384 + n, 128, 128) + bpm[j];
  }
}

// ---- stage 5: Nn = Wx@M1; n0 = bx@M1 + m0
__global__ void pre5(const float* __restrict__ Wx, const float* __restrict__ bx,
                     const float* __restrict__ M1, const float* __restrict__ m0,
                     float* __restrict__ Nn, float* __restrict__ n0){
  int i = blockIdx.x * 256 + threadIdx.x;
  if (i < 49152){                       // Nn[c][rr][n], 3*128*128
    int c = i >> 14, rr = (i >> 7) & 127, n = i & 127;
    Nn[i] = dotSB(Wx + ((size_t)c*128 + rr)*128, M1 + (size_t)c*16384 + n, 128, 128);
  } else if (i < 49536){                // n0[c][n], 3*128
    int j = i - 49152; int c = j >> 7, n = j & 127;
    n0[j] = dotSB(bx + c*128, M1 + (size_t)c*16384 + n, 128, 128) + m0[j];
  }
}

// ---- U[c,t,b,:] = x_row@R_c + r0_c, stored bf16. 32 rows/block, col = tid.
__global__ void kernU(const float* __restrict__ x, const float* __restrict__ R,
                      const float* __restrict__ r0, unsigned short* __restrict__ U){
  const int m0 = blockIdx.x * 32;              // 51200/32=1600: no channel straddle
  const int col = threadIdx.x;                 // 0..255
  const int c = m0 / 51200;
  const float* __restrict__ Rc = R + (size_t)c * 32768;
  const float* __restrict__ xb = x + (size_t)m0 * 128;
  float acc[32];
  const float rz = r0[c*256 + col];
  #pragma unroll
  for (int rr = 0; rr < 32; ++rr) acc[rr] = rz;
  for (int k = 0; k < 128; k += 4){
    float rk0 = Rc[(k+0)*256 + col];
    float rk1 = Rc[(k+1)*256 + col];
    float rk2 = Rc[(k+2)*256 + col];
    float rk3 = Rc[(k+3)*256 + col];
    #pragma unroll
    for (int rr = 0; rr < 32; ++rr){
      const float* xr = xb + rr*128 + k;       // wave-uniform -> scalar loads
      acc[rr] = fmaf(xr[0], rk0, acc[rr]);
      acc[rr] = fmaf(xr[1], rk1, acc[rr]);
      acc[rr] = fmaf(xr[2], rk2, acc[rr]);
      acc[rr] = fmaf(xr[3], rk3, acc[rr]);
    }
  }
  unsigned short* Ub = U + (size_t)m0 * 256 + col;
  #pragma unroll
  for (int rr = 0; rr < 32; ++rr) Ub[(size_t)rr * 256] = f2bf(acc[rr]);
}

// ---- recurrence via MFMA: h_{t+1} = tanh(U_t + h_t@Q_c).
// 96 blocks = 3 channels x 32 (16 batch rows each), 512 threads = 8 waves.
// Wave w owns output cols [32w, 32w+32) as two 16-col MFMA n-tiles.
// Q (bf16) B-fragments live in registers for the whole kernel (64 VGPRs).
// h carried in LDS as bf16 hi + bf16 residual lo (h quantization compensated).
__global__ __launch_bounds__(512, 2)
void kernB2(const unsigned short* __restrict__ U, const float* __restrict__ Qg,
            const float* __restrict__ h0, unsigned short* __restrict__ Hs){
  __shared__ unsigned short hHi[16][264];      // +8 pad: 16B-aligned rows, row stride 132 dw
  __shared__ unsigned short hLo[16][264];
  const int c  = blockIdx.x >> 5;
  const int b0 = (blockIdx.x & 31) << 4;
  const int w  = threadIdx.x >> 6;
  const int l  = threadIdx.x & 63;
  const int q  = l >> 4, m = l & 15;
  const float* __restrict__ Qc = Qg + (size_t)c * 65536;

  // ---- preload Q B-frags (bf16) into registers: qf[kt][nt]
  short8 qf[8][2];
  #pragma unroll
  for (int kt = 0; kt < 8; ++kt){
    #pragma unroll
    for (int nt = 0; nt < 2; ++nt){
      union { short8 v; unsigned short u[8]; } tmp;
      const int col = 32*w + 16*nt + m;
      #pragma unroll
      for (int j = 0; j < 8; ++j)
        tmp.u[j] = f2bf(Qc[(size_t)(32*kt + 8*q + j)*256 + col]);
      qf[kt][nt] = tmp.v;
    }
  }

  // ---- h0 -> C-frag regs (bf16 hi for Hs stores) + LDS hi/lo
  unsigned short hiR[8];                       // [nt*4 + r]
  #pragma unroll
  for (int nt = 0; nt < 2; ++nt){
    const int col = 32*w + 16*nt + m;
    #pragma unroll
    for (int r = 0; r < 4; ++r){
      const int row = 4*q + r;
      float v = h0[((size_t)c*512 + b0 + row)*256 + col];
      unsigned short hi = f2bf(v);
      hiR[nt*4 + r] = hi;
      hHi[row][col] = hi;
      hLo[row][col] = f2bf(v - bf2f(hi));
    }
  }
  __syncthreads();

  // ---- prefetch U for t=0
  unsigned short un[8];
  #pragma unroll
  for (int nt = 0; nt < 2; ++nt)
    #pragma unroll
    for (int r = 0; r < 4; ++r)
      un[nt*4 + r] = U[((size_t)(c*100 + 0)*512 + b0 + 4*q + r)*256 + 32*w + 16*nt + m];

  #pragma unroll 1
  for (int t = 0; t < 100; ++t){
    // store Hs = h_t (pre-update), bf16
    const size_t rowbase = (size_t)(c*100 + t)*512 + b0;
    #pragma unroll
    for (int nt = 0; nt < 2; ++nt)
      #pragma unroll
      for (int r = 0; r < 4; ++r)
        Hs[(rowbase + 4*q + r)*256 + 32*w + 16*nt + m] = hiR[nt*4 + r];

    // acc init = U_t (C-frag layout: col=lane&15, row=quad*4+reg)
    float4v acc0 = { bf2f(un[0]), bf2f(un[1]), bf2f(un[2]), bf2f(un[3]) };
    float4v acc1 = { bf2f(un[4]), bf2f(un[5]), bf2f(un[6]), bf2f(un[7]) };

    // prefetch U for t+1 (clamped; harmless dup at t=99)
    const int tn = (t < 99) ? t + 1 : 99;
    #pragma unroll
    for (int nt = 0; nt < 2; ++nt)
      #pragma unroll
      for (int r = 0; r < 4; ++r)
        un[nt*4 + r] = U[((size_t)(c*100 + tn)*512 + b0 + 4*q + r)*256 + 32*w + 16*nt + m];

    // a = U + h_hi@Q + h_lo@Q
    #pragma unroll
    for (int kt = 0; kt < 8; ++kt){
      short8 ahi = *(const short8*)&hHi[m][32*kt + 8*q];
      short8 alo = *(const short8*)&hLo[m][32*kt + 8*q];
      acc0 = __builtin_amdgcn_mfma_f32_16x16x32_bf16(ahi, qf[kt][0], acc0, 0, 0, 0);
      acc1 = __builtin_amdgcn_mfma_f32_16x16x32_bf16(ahi, qf[kt][1], acc1, 0, 0, 0);
      acc0 = __builtin_amdgcn_mfma_f32_16x16x32_bf16(alo, qf[kt][0], acc0, 0, 0, 0);
      acc1 = __builtin_amdgcn_mfma_f32_16x16x32_bf16(alo, qf[kt][1], acc1, 0, 0, 0);
    }

    // h_{t+1} = tanh(a); split hi/lo
    float hn[8];
    hn[0] = ftanh(acc0.x); hn[1] = ftanh(acc0.y); hn[2] = ftanh(acc0.z); hn[3] = ftanh(acc0.w);
    hn[4] = ftanh(acc1.x); hn[5] = ftanh(acc1.y); hn[6] = ftanh(acc1.z); hn[7] = ftanh(acc1.w);

    __syncthreads();                           // all frag reads of h_t complete
    #pragma unroll
    for (int nt = 0; nt < 2; ++nt){
      const int col = 32*w + 16*nt + m;
      #pragma unroll
      for (int r = 0; r < 4; ++r){
        const int row = 4*q + r;
        float v = hn[nt*4 + r];
        unsigned short hi = f2bf(v);
        hiR[nt*4 + r] = hi;
        hHi[row][col] = hi;
        hLo[row][col] = f2bf(v - bf2f(hi));
      }
    }
    __syncthreads();                           // h_{t+1} visible
  }
}

// ---- out[c,t,b,:] = x_row@Nn_c + Hs_row@M2_c + n0_c. 32 rows/block, 128 threads.
__global__ void kernC(const float* __restrict__ x, const unsigned short* __restrict__ Hs,
                      const float* __restrict__ Nn, const float* __restrict__ M2,
                      const float* __restrict__ n0, float* __restrict__ out){
  const int m0 = blockIdx.x * 32;
  const int col = threadIdx.x;                 // 0..127
  const int c = m0 / 51200;
  const float* __restrict__ Nc  = Nn + (size_t)c * 16384;
  const float* __restrict__ M2c = M2 + (size_t)c * 32768;
  const float* __restrict__ xb  = x + (size_t)m0 * 128;
  const uint32_t* __restrict__ Hb = (const uint32_t*)(Hs + (size_t)m0 * 256);
  float acc[32];
  const float nz = n0[c*128 + col];
  #pragma unroll
  for (int rr = 0; rr < 32; ++rr) acc[rr] = nz;
  for (int k = 0; k < 128; k += 2){
    float nk0 = Nc[(k+0)*128 + col];
    float nk1 = Nc[(k+1)*128 + col];
    #pragma unroll
    for (int rr = 0; rr < 32; ++rr){
      const float* xr = xb + rr*128 + k;
      acc[rr] = fmaf(xr[0], nk0, acc[rr]);
      acc[rr] = fmaf(xr[1], nk1, acc[rr]);
    }
  }
  for (int kp = 0; kp < 128; ++kp){
    float mk0 = M2c[(size_t)(2*kp+0)*128 + col];
    float mk1 = M2c[(size_t)(2*kp+1)*128 + col];
    #pragma unroll
    for (int rr = 0; rr < 32; ++rr){
      uint32_t v = Hb[rr*128 + kp];            // wave-uniform scalar load, 2 bf16
      union{uint32_t i; float f;} lo, hi;
      lo.i = v << 16; hi.i = v & 0xffff0000u;
      acc[rr] = fmaf(lo.f, mk0, acc[rr]);
      acc[rr] = fmaf(hi.f, mk1, acc[rr]);
    }
  }
  float* ob = out + (size_t)m0 * 128 + col;
  #pragma unroll
  for (int rr = 0; rr < 32; ++rr) ob[(size_t)rr * 128] = acc[rr];
}

extern "C" void kernel_launch(void* const* d_in, const int* in_sizes, int n_in,
                              void* d_out, int out_size, void* d_ws, size_t ws_size,
                              hipStream_t stream){
  const float* x    = (const float*)d_in[0];
  const float* Wx   = (const float*)d_in[1];
  const float* bx   = (const float*)d_in[2];
  const float* encW = (const float*)d_in[3];
  const float* encb = (const float*)d_in[4];
  const float* Wqm  = (const float*)d_in[5];
  const float* bqm  = (const float*)d_in[6];
  const float* Wz   = (const float*)d_in[7];
  const float* bz   = (const float*)d_in[8];
  const float* decW = (const float*)d_in[9];
  const float* decb = (const float*)d_in[10];
  const float* Wpm  = (const float*)d_in[11];
  const float* bpm  = (const float*)d_in[12];
  const float* Wih  = (const float*)d_in[13];
  const float* Whh  = (const float*)d_in[14];
  const float* bih  = (const float*)d_in[15];
  const float* bhh  = (const float*)d_in[16];
  const float* h0   = (const float*)d_in[17];

  float* ws = (float*)d_ws;
  size_t off = 0;
  auto alloc = [&](size_t n){ float* p = ws + off; off += n; return p; };
  float* T1  = alloc(24576);  float* T2  = alloc(49152);  float* c0a = alloc(192);
  float* A   = alloc(49152);  float* Bm  = alloc(98304);  float* c0  = alloc(384);
  float* P   = alloc(98304);  float* Q   = alloc(196608); float* r   = alloc(768);
  float* D1  = alloc(49152);  float* E1  = alloc(98304);  float* m0a = alloc(384);
  float* R   = alloc(98304);  float* r0  = alloc(768);
  float* M1  = alloc(49152);  float* M2  = alloc(98304);  float* m0  = alloc(384);
  float* Nn  = alloc(49152);  float* n0  = alloc(384);
  // U (bf16, 39.3M elems) lives in d_out's buffer (exactly 78.6MB); consumed by
  // kernB2 before kernC overwrites d_out with the final result.
  unsigned short* U  = (unsigned short*)d_out;
  unsigned short* Hs = (unsigned short*)(ws + off); off += 19660800;  // bf16 in float slots

  hipLaunchKernelGGL(pre1, dim3(289),  dim3(256), 0, stream, encW, encb, Wqm, bqm, T1, T2, c0a);
  hipLaunchKernelGGL(pre2, dim3(578),  dim3(256), 0, stream, T1, T2, c0a, Wz, bz, A, Bm, c0);
  hipLaunchKernelGGL(pre3, dim3(1733), dim3(256), 0, stream, A, Bm, c0, Wih, Whh, bih, bhh,
                     decW, decb, P, Q, r, D1, E1, m0a);
  hipLaunchKernelGGL(pre4, dim3(965),  dim3(256), 0, stream, Wx, bx, P, r, D1, E1, m0a,
                     Wpm, bpm, R, r0, M1, M2, m0);
  hipLaunchKernelGGL(pre5, dim3(194),  dim3(256), 0, stream, Wx, bx, M1, m0, Nn, n0);
  hipLaunchKernelGGL(kernU, dim3(4800), dim3(256), 0, stream, x, R, r0, U);
  hipLaunchKernelGGL(kernB2, dim3(96),  dim3(512), 0, stream, U, Q, h0, Hs);
  hipLaunchKernelGGL(kernC, dim3(4800), dim3(128), 0, stream, x, Hs, Nn, M2, n0, (float*)d_out);
}

// Round 4
// 486.709 us; speedup vs baseline: 5.7067x; 2.8061x over previous
//
#include <hip/hip_runtime.h>
#include <hip/hip_bf16.h>
#include <cstdint>

// MCRNNVAE eval forward, algebraically collapsed:
//   h_{t+1} = tanh(x_t@R_c + r0_c + h_t@Q_c)
//   mu_t    = x_t@N_c + h_t@M2_c + n0_c
// R,Q,N,M2,r0,n0 precomputed from the raw weights (exact linear algebra).
// Round 4: U = x@R + r0 via MFMA kernel (kernU2) into d_out (exact fit, consumed
// by kernB2 before kernC3 overwrites); kernB2 = proven round-2 serial kernel;
// kernC3 = MFMA epilogue with in-kernel x conversion staged via padded LDS.
// ws footprint = round-2-proven 20,622,528 floats (precompute + full-size Hs).

typedef __attribute__((ext_vector_type(8))) short short8;
typedef __attribute__((ext_vector_type(4))) float float4v;

__device__ __forceinline__ float bf2f(unsigned short u){
  union { unsigned int i; float f; } v; v.i = ((unsigned int)u) << 16; return v.f;
}
__device__ __forceinline__ unsigned short f2bf(float f){
  union { float f; unsigned int i; } v; v.f = f;
  unsigned int r = v.i + 0x7fffu + ((v.i >> 16) & 1u);
  return (unsigned short)(r >> 16);
}
__device__ __forceinline__ void st_bf2(unsigned short* p, float a, float b){
  unsigned int pa = f2bf(a), pb = f2bf(b);
  *(unsigned int*)p = pa | (pb << 16);
}
__device__ __forceinline__ float ftanh(float x){
  x = fminf(15.f, fmaxf(-15.f, x));
  float e = __expf(2.f * x);
  return (e - 1.f) * __builtin_amdgcn_rcpf(e + 1.f);
}

__device__ __forceinline__ float dotSB(const float* __restrict__ a,
                                       const float* __restrict__ b, int K, int ldb){
  float s = 0.f;
  #pragma unroll 4
  for (int k = 0; k < K; ++k) s = fmaf(a[k], b[(size_t)k * ldb], s);
  return s;
}

// ---- precompute stage 1: T1 = We1@Wqm, T2 = We2@Wqm, c0a = be@Wqm + bqm
__global__ void pre1(const float* __restrict__ encW, const float* __restrict__ encb,
                     const float* __restrict__ Wqm, const float* __restrict__ bqm,
                     float* __restrict__ T1, float* __restrict__ T2, float* __restrict__ c0a){
  int i = blockIdx.x * 256 + threadIdx.x;
  if (i < 24576){
    int c = i >> 13, rr = (i >> 6) & 127, l = i & 63;
    T1[i] = dotSB(encW + ((size_t)c*384 + rr)*128, Wqm + (size_t)c*8192 + l, 128, 64);
  } else if (i < 73728){
    int j = i - 24576; int c = j >> 14, rr = (j >> 6) & 255, l = j & 63;
    T2[j] = dotSB(encW + ((size_t)c*384 + 128 + rr)*128, Wqm + (size_t)c*8192 + l, 128, 64);
  } else if (i < 73920){
    int j = i - 73728; int c = j >> 6, l = j & 63;
    c0a[j] = dotSB(encb + c*128, Wqm + (size_t)c*8192 + l, 128, 64) + bqm[j];
  }
}

// ---- stage 2: A = T1@Wz, Bm = T2@Wz, c0 = c0a@Wz + bz
__global__ void pre2(const float* __restrict__ T1, const float* __restrict__ T2,
                     const float* __restrict__ c0a, const float* __restrict__ Wz,
                     const float* __restrict__ bz,
                     float* __restrict__ A, float* __restrict__ Bm, float* __restrict__ c0){
  int i = blockIdx.x * 256 + threadIdx.x;
  if (i < 49152){
    int c = i >> 14, rr = (i >> 7) & 127, n = i & 127;
    A[i] = dotSB(T1 + ((size_t)c*128 + rr)*64, Wz + n, 64, 128);
  } else if (i < 147456){
    int j = i - 49152; int c = j >> 15, rr = (j >> 7) & 255, n = j & 127;
    Bm[j] = dotSB(T2 + ((size_t)c*256 + rr)*64, Wz + n, 64, 128);
  } else if (i < 147840){
    int j = i - 147456; int c = j >> 7, n = j & 127;
    c0[j] = dotSB(c0a + c*64, Wz + n, 64, 128) + bz[n];
  }
}

// ---- stage 3: P = Wi1 + A@Wi2; Q = Whh + Bm@Wi2; r = c0@Wi2 + bih + bhh;
//               D1 = A@Wd1; E1 = Wd2 + Bm@Wd1; m0a = c0@Wd1 + bd
__global__ void pre3(const float* __restrict__ A, const float* __restrict__ Bm,
                     const float* __restrict__ c0, const float* __restrict__ Wih,
                     const float* __restrict__ Whh, const float* __restrict__ bih,
                     const float* __restrict__ bhh, const float* __restrict__ decW,
                     const float* __restrict__ decb,
                     float* __restrict__ P, float* __restrict__ Q, float* __restrict__ r,
                     float* __restrict__ D1, float* __restrict__ E1, float* __restrict__ m0a){
  int i = blockIdx.x * 256 + threadIdx.x;
  const float* Wi2 = Wih + 128*256;
  if (i < 98304){
    int c = i >> 15, rr = (i >> 8) & 127, n = i & 255;
    P[i] = Wih[rr*256 + n] + dotSB(A + ((size_t)c*128 + rr)*128, Wi2 + n, 128, 256);
  } else if (i < 294912){
    int j = i - 98304; int c = j >> 16, rr = (j >> 8) & 255, n = j & 255;
    Q[j] = Whh[rr*256 + n] + dotSB(Bm + ((size_t)c*256 + rr)*128, Wi2 + n, 128, 256);
  } else if (i < 295680){
    int j = i - 294912; int c = j >> 8, n = j & 255;
    r[j] = dotSB(c0 + c*128, Wi2 + n, 128, 256) + bih[n] + bhh[n];
  } else if (i < 344832){
    int j = i - 295680; int c = j >> 14, rr = (j >> 7) & 127, n = j & 127;
    D1[j] = dotSB(A + ((size_t)c*128 + rr)*128, decW + (size_t)c*49152 + n, 128, 128);
  } else if (i < 443136){
    int j = i - 344832; int c = j >> 15, rr = (j >> 7) & 255, n = j & 127;
    E1[j] = decW[(size_t)c*49152 + (size_t)(128 + rr)*128 + n]
          + dotSB(Bm + ((size_t)c*256 + rr)*128, decW + (size_t)c*49152 + n, 128, 128);
  } else if (i < 443520){
    int j = i - 443136; int c = j >> 7, n = j & 127;
    m0a[j] = dotSB(c0 + c*128, decW + (size_t)c*49152 + n, 128, 128) + decb[j];
  }
}

// ---- stage 4: R = Wx@P; r0 = bx@P + r; M1 = D1@Wpm; M2 = E1@Wpm; m0 = m0a@Wpm + bpm
__global__ void pre4(const float* __restrict__ Wx, const float* __restrict__ bx,
                     const float* __restrict__ P, const float* __restrict__ r,
                     const float* __restrict__ D1, const float* __restrict__ E1,
                     const float* __restrict__ m0a, const float* __restrict__ Wpm,
                     const float* __restrict__ bpm,
                     float* __restrict__ R, float* __restrict__ r0,
                     float* __restrict__ M1, float* __restrict__ M2, float* __restrict__ m0){
  int i = blockIdx.x * 256 + threadIdx.x;
  if (i < 98304){
    int c = i >> 15, rr = (i >> 8) & 127, n = i & 255;
    R[i] = dotSB(Wx + ((size_t)c*128 + rr)*128, P + (size_t)c*32768 + n, 128, 256);
  } else if (i < 99072){
    int j = i - 98304; int c = j >> 8, n = j & 255;
    r0[j] = dotSB(bx + c*128, P + (size_t)c*32768 + n, 128, 256) + r[j];
  } else if (i < 148224){
    int j = i - 99072; int c = j >> 14, rr = (j >> 7) & 127, n = j & 127;
    M1[j] = dotSB(D1 + ((size_t)c*128 + rr)*128, Wpm + (size_t)c*16384 + n, 128, 128);
  } else if (i < 246528){
    int j = i - 148224; int c = j >> 15, rr = (j >> 7) & 255, n = j & 127;
    M2[j] = dotSB(E1 + ((size_t)c*256 + rr)*128, Wpm + (size_t)c*16384 + n, 128, 128);
  } else if (i < 246912){
    int j = i - 246528; int c = j >> 7, n = j & 127;
    m0[j] = dotSB(m0a + c*128, Wpm + (size_t)c*16384 + n, 128, 128) + bpm[j];
  }
}

// ---- stage 5: Nn = Wx@M1; n0 = bx@M1 + m0
__global__ void pre5(const float* __restrict__ Wx, const float* __restrict__ bx,
                     const float* __restrict__ M1, const float* __restrict__ m0,
                     float* __restrict__ Nn, float* __restrict__ n0){
  int i = blockIdx.x * 256 + threadIdx.x;
  if (i < 49152){
    int c = i >> 14, rr = (i >> 7) & 127, n = i & 127;
    Nn[i] = dotSB(Wx + ((size_t)c*128 + rr)*128, M1 + (size_t)c*16384 + n, 128, 128);
  } else if (i < 49536){
    int j = i - 49152; int c = j >> 7, n = j & 127;
    n0[j] = dotSB(bx + c*128, M1 + (size_t)c*16384 + n, 128, 128) + m0[j];
  }
}

#define MFMA_BF16 __builtin_amdgcn_mfma_f32_16x16x32_bf16

// ---- kernU2: U = x@R + r0 (bf16 out) via MFMA. 1200 blocks x 512 thr (8 waves).
// Wave w owns cols [32w,32w+32); 8 m-tiles of 16 rows per block. x staged fp32->bf16
// in LDS (row stride 136: bank groups spread, 2-way max aliasing = free).
__global__ __launch_bounds__(512, 2)
void kernU2(const float* __restrict__ x, const float* __restrict__ Rg,
            const float* __restrict__ r0g, unsigned short* __restrict__ U){
  __shared__ unsigned short xs[128][136];
  const int m0 = blockIdx.x * 128;
  const int c  = m0 / 51200;                   // 400 blocks/channel, no straddle
  const int w  = threadIdx.x >> 6;
  const int l  = threadIdx.x & 63;
  const int q  = l >> 4, m = l & 15;
  const float* __restrict__ Rc = Rg + (size_t)c * 32768;   // [128][256]

  // R B-frags (bf16): B[k=32kt+8q+j][n=32w+16nt+m]
  short8 rf[4][2];
  #pragma unroll
  for (int kt = 0; kt < 4; ++kt)
    #pragma unroll
    for (int nt = 0; nt < 2; ++nt){
      union { short8 v; unsigned short u[8]; } tmp;
      const int col = 32*w + 16*nt + m;
      #pragma unroll
      for (int j = 0; j < 8; ++j)
        tmp.u[j] = f2bf(Rc[(size_t)(32*kt + 8*q + j)*256 + col]);
      rf[kt][nt] = tmp.v;
    }
  const float r0v0 = r0g[c*256 + 32*w + m];
  const float r0v1 = r0g[c*256 + 32*w + 16 + m];

  // stage x block rows [m0,m0+128) cols [0,128) -> LDS bf16
  {
    const int r  = threadIdx.x >> 2;           // 0..127
    const int c0 = (threadIdx.x & 3) * 32;     // 0/32/64/96, coalesced float4 loads
    const float* xr = x + (size_t)(m0 + r)*128 + c0;
    #pragma unroll
    for (int i = 0; i < 8; ++i){
      float4 v = *(const float4*)(xr + 4*i);
      st_bf2(&xs[r][c0 + 4*i],     v.x, v.y);
      st_bf2(&xs[r][c0 + 4*i + 2], v.z, v.w);
    }
  }
  __syncthreads();

  #pragma unroll 1
  for (int mt = 0; mt < 8; ++mt){
    float4v a0 = { r0v0, r0v0, r0v0, r0v0 };
    float4v a1 = { r0v1, r0v1, r0v1, r0v1 };
    #pragma unroll
    for (int kt = 0; kt < 4; ++kt){
      short8 af = *(const short8*)&xs[16*mt + m][32*kt + 8*q];
      a0 = MFMA_BF16(af, rf[kt][0], a0, 0,0,0);
      a1 = MFMA_BF16(af, rf[kt][1], a1, 0,0,0);
    }
    unsigned short* ub = U + (size_t)(m0 + 16*mt + 4*q)*256;
    ub[0*256 + 32*w + m]      = f2bf(a0.x);
    ub[1*256 + 32*w + m]      = f2bf(a0.y);
    ub[2*256 + 32*w + m]      = f2bf(a0.z);
    ub[3*256 + 32*w + m]      = f2bf(a0.w);
    ub[0*256 + 32*w + 16 + m] = f2bf(a1.x);
    ub[1*256 + 32*w + 16 + m] = f2bf(a1.y);
    ub[2*256 + 32*w + 16 + m] = f2bf(a1.z);
    ub[3*256 + 32*w + 16 + m] = f2bf(a1.w);
  }
}

// ---- recurrence via MFMA (round-2 proven): h_{t+1} = tanh(U_t + h_t@Q_c).
// 96 blocks = 3 channels x 32 (16 batch rows each), 512 threads = 8 waves.
__global__ __launch_bounds__(512, 2)
void kernB2(const unsigned short* __restrict__ U, const float* __restrict__ Qg,
            const float* __restrict__ h0, unsigned short* __restrict__ Hs){
  __shared__ unsigned short hHi[16][264];
  __shared__ unsigned short hLo[16][264];
  const int c  = blockIdx.x >> 5;
  const int b0 = (blockIdx.x & 31) << 4;
  const int w  = threadIdx.x >> 6;
  const int l  = threadIdx.x & 63;
  const int q  = l >> 4, m = l & 15;
  const float* __restrict__ Qc = Qg + (size_t)c * 65536;

  short8 qf[8][2];
  #pragma unroll
  for (int kt = 0; kt < 8; ++kt)
    #pragma unroll
    for (int nt = 0; nt < 2; ++nt){
      union { short8 v; unsigned short u[8]; } tmp;
      const int col = 32*w + 16*nt + m;
      #pragma unroll
      for (int j = 0; j < 8; ++j)
        tmp.u[j] = f2bf(Qc[(size_t)(32*kt + 8*q + j)*256 + col]);
      qf[kt][nt] = tmp.v;
    }

  unsigned short hiR[8];
  #pragma unroll
  for (int nt = 0; nt < 2; ++nt){
    const int col = 32*w + 16*nt + m;
    #pragma unroll
    for (int r = 0; r < 4; ++r){
      const int row = 4*q + r;
      float v = h0[((size_t)c*512 + b0 + row)*256 + col];
      unsigned short hi = f2bf(v);
      hiR[nt*4 + r] = hi;
      hHi[row][col] = hi;
      hLo[row][col] = f2bf(v - bf2f(hi));
    }
  }
  __syncthreads();

  unsigned short un[8];
  #pragma unroll
  for (int nt = 0; nt < 2; ++nt)
    #pragma unroll
    for (int r = 0; r < 4; ++r)
      un[nt*4 + r] = U[((size_t)(c*100 + 0)*512 + b0 + 4*q + r)*256 + 32*w + 16*nt + m];

  #pragma unroll 1
  for (int t = 0; t < 100; ++t){
    const size_t rowbase = (size_t)(c*100 + t)*512 + b0;
    #pragma unroll
    for (int nt = 0; nt < 2; ++nt)
      #pragma unroll
      for (int r = 0; r < 4; ++r)
        Hs[(rowbase + 4*q + r)*256 + 32*w + 16*nt + m] = hiR[nt*4 + r];

    float4v acc0 = { bf2f(un[0]), bf2f(un[1]), bf2f(un[2]), bf2f(un[3]) };
    float4v acc1 = { bf2f(un[4]), bf2f(un[5]), bf2f(un[6]), bf2f(un[7]) };

    const int tn = (t < 99) ? t + 1 : 99;
    #pragma unroll
    for (int nt = 0; nt < 2; ++nt)
      #pragma unroll
      for (int r = 0; r < 4; ++r)
        un[nt*4 + r] = U[((size_t)(c*100 + tn)*512 + b0 + 4*q + r)*256 + 32*w + 16*nt + m];

    #pragma unroll
    for (int kt = 0; kt < 8; ++kt){
      short8 ahi = *(const short8*)&hHi[m][32*kt + 8*q];
      short8 alo = *(const short8*)&hLo[m][32*kt + 8*q];
      acc0 = MFMA_BF16(ahi, qf[kt][0], acc0, 0,0,0);
      acc1 = MFMA_BF16(ahi, qf[kt][1], acc1, 0,0,0);
      acc0 = MFMA_BF16(alo, qf[kt][0], acc0, 0,0,0);
      acc1 = MFMA_BF16(alo, qf[kt][1], acc1, 0,0,0);
    }

    float hn[8];
    hn[0] = ftanh(acc0.x); hn[1] = ftanh(acc0.y); hn[2] = ftanh(acc0.z); hn[3] = ftanh(acc0.w);
    hn[4] = ftanh(acc1.x); hn[5] = ftanh(acc1.y); hn[6] = ftanh(acc1.z); hn[7] = ftanh(acc1.w);

    __syncthreads();
    #pragma unroll
    for (int nt = 0; nt < 2; ++nt){
      const int col = 32*w + 16*nt + m;
      #pragma unroll
      for (int r = 0; r < 4; ++r){
        const int row = 4*q + r;
        float v = hn[nt*4 + r];
        unsigned short hi = f2bf(v);
        hiR[nt*4 + r] = hi;
        hHi[row][col] = hi;
        hLo[row][col] = f2bf(v - bf2f(hi));
      }
    }
    __syncthreads();
  }
}

// ---- kernC3: out = x@Nn + Hs@M2 + n0 via MFMA. 1200 blocks x 512 thr.
// Wave w owns cols [16w,16w+16); 8 m-tiles/block. x staged fp32->bf16 in LDS;
// Hs A-frags read from global (bf16, L1/L2-served).
__global__ __launch_bounds__(512, 2)
void kernC3(const float* __restrict__ x, const unsigned short* __restrict__ Hs,
            const float* __restrict__ Nn, const float* __restrict__ M2,
            const float* __restrict__ n0, float* __restrict__ out){
  __shared__ unsigned short xs[128][136];
  const int m0 = blockIdx.x * 128;
  const int c  = m0 / 51200;
  const int w  = threadIdx.x >> 6;
  const int l  = threadIdx.x & 63;
  const int q  = l >> 4, m = l & 15;
  const int col = 16*w + m;
  const float* __restrict__ Nc  = Nn + (size_t)c * 16384;   // [128][128]
  const float* __restrict__ M2c = M2 + (size_t)c * 32768;   // [256][128]

  // B-frags: kt<4 from Nn (x part), kt>=4 from M2 (h part)
  short8 bw[12];
  #pragma unroll
  for (int kt = 0; kt < 4; ++kt){
    union { short8 v; unsigned short u[8]; } tmp;
    #pragma unroll
    for (int j = 0; j < 8; ++j)
      tmp.u[j] = f2bf(Nc[(size_t)(32*kt + 8*q + j)*128 + col]);
    bw[kt] = tmp.v;
  }
  #pragma unroll
  for (int kt = 0; kt < 8; ++kt){
    union { short8 v; unsigned short u[8]; } tmp;
    #pragma unroll
    for (int j = 0; j < 8; ++j)
      tmp.u[j] = f2bf(M2c[(size_t)(32*kt + 8*q + j)*128 + col]);
    bw[4 + kt] = tmp.v;
  }
  const float nz = n0[c*128 + col];

  // stage x block -> LDS bf16
  {
    const int r  = threadIdx.x >> 2;
    const int c0 = (threadIdx.x & 3) * 32;
    const float* xr = x + (size_t)(m0 + r)*128 + c0;
    #pragma unroll
    for (int i = 0; i < 8; ++i){
      float4 v = *(const float4*)(xr + 4*i);
      st_bf2(&xs[r][c0 + 4*i],     v.x, v.y);
      st_bf2(&xs[r][c0 + 4*i + 2], v.z, v.w);
    }
  }
  __syncthreads();

  #pragma unroll 1
  for (int mt = 0; mt < 8; ++mt){
    float4v aa = { nz, nz, nz, nz }, ab = { 0.f, 0.f, 0.f, 0.f };
    #pragma unroll
    for (int kt = 0; kt < 4; ++kt){
      short8 af = *(const short8*)&xs[16*mt + m][32*kt + 8*q];
      if (kt & 1) ab = MFMA_BF16(af, bw[kt], ab, 0,0,0);
      else        aa = MFMA_BF16(af, bw[kt], aa, 0,0,0);
    }
    const size_t mrow = (size_t)(m0 + 16*mt) + m;
    #pragma unroll
    for (int kt = 0; kt < 8; ++kt){
      short8 af = *(const short8*)&Hs[mrow*256 + 32*kt + 8*q];
      if (kt & 1) ab = MFMA_BF16(af, bw[4+kt], ab, 0,0,0);
      else        aa = MFMA_BF16(af, bw[4+kt], aa, 0,0,0);
    }
    float* ob = out + (size_t)(m0 + 16*mt + 4*q)*128 + col;
    ob[0]   = aa.x + ab.x;
    ob[128] = aa.y + ab.y;
    ob[256] = aa.z + ab.z;
    ob[384] = aa.w + ab.w;
  }
}

extern "C" void kernel_launch(void* const* d_in, const int* in_sizes, int n_in,
                              void* d_out, int out_size, void* d_ws, size_t ws_size,
                              hipStream_t stream){
  const float* x    = (const float*)d_in[0];
  const float* Wx   = (const float*)d_in[1];
  const float* bx   = (const float*)d_in[2];
  const float* encW = (const float*)d_in[3];
  const float* encb = (const float*)d_in[4];
  const float* Wqm  = (const float*)d_in[5];
  const float* bqm  = (const float*)d_in[6];
  const float* Wz   = (const float*)d_in[7];
  const float* bz   = (const float*)d_in[8];
  const float* decW = (const float*)d_in[9];
  const float* decb = (const float*)d_in[10];
  const float* Wpm  = (const float*)d_in[11];
  const float* bpm  = (const float*)d_in[12];
  const float* Wih  = (const float*)d_in[13];
  const float* Whh  = (const float*)d_in[14];
  const float* bih  = (const float*)d_in[15];
  const float* bhh  = (const float*)d_in[16];
  const float* h0   = (const float*)d_in[17];

  float* ws = (float*)d_ws;
  size_t off = 0;
  auto alloc = [&](size_t n){ float* p = ws + off; off += n; return p; };
  float* T1  = alloc(24576);  float* T2  = alloc(49152);  float* c0a = alloc(192);
  float* A   = alloc(49152);  float* Bm  = alloc(98304);  float* c0  = alloc(384);
  float* P   = alloc(98304);  float* Q   = alloc(196608); float* r   = alloc(768);
  float* D1  = alloc(49152);  float* E1  = alloc(98304);  float* m0a = alloc(384);
  float* R   = alloc(98304);  float* r0  = alloc(768);
  float* M1  = alloc(49152);  float* M2  = alloc(98304);  float* m0  = alloc(384);
  float* Nn  = alloc(49152);  float* n0  = alloc(384);
  // Hs: 39,321,600 bf16 elements = 19,660,800 float slots (FULL size — round-3 bug
  // was halving this). Total ws = 20,622,528 floats, identical to round-2 layout.
  unsigned short* Hs = (unsigned short*)(ws + off); off += 19660800;
  // U (bf16, 39.3M elems = 78.64 MB) lives in d_out (exact fit); consumed by
  // kernB2 before kernC3 overwrites d_out with the final result.
  unsigned short* U  = (unsigned short*)d_out;

  hipLaunchKernelGGL(pre1, dim3(289),  dim3(256), 0, stream, encW, encb, Wqm, bqm, T1, T2, c0a);
  hipLaunchKernelGGL(pre2, dim3(578),  dim3(256), 0, stream, T1, T2, c0a, Wz, bz, A, Bm, c0);
  hipLaunchKernelGGL(pre3, dim3(1733), dim3(256), 0, stream, A, Bm, c0, Wih, Whh, bih, bhh,
                     decW, decb, P, Q, r, D1, E1, m0a);
  hipLaunchKernelGGL(pre4, dim3(965),  dim3(256), 0, stream, Wx, bx, P, r, D1, E1, m0a,
                     Wpm, bpm, R, r0, M1, M2, m0);
  hipLaunchKernelGGL(pre5, dim3(194),  dim3(256), 0, stream, Wx, bx, M1, m0, Nn, n0);
  hipLaunchKernelGGL(kernU2, dim3(1200), dim3(512), 0, stream, x, R, r0, U);
  hipLaunchKernelGGL(kernB2, dim3(96),   dim3(512), 0, stream, U, Q, h0, Hs);
  hipLaunchKernelGGL(kernC3, dim3(1200), dim3(512), 0, stream, x, Hs, Nn, M2, n0, (float*)d_out);
}